// Round 4
// baseline (308.349 us; speedup 1.0000x reference)
//
#include <hip/hip_runtime.h>
#include <hip/hip_bf16.h>

#define NA 8400
#define BS 64
#define NC 80
#define TOPK 13
#define EPSF 1e-9f
#define SEG 2100          // NA / 4 waves
#define KMAX 33           // ceil(SEG/64)

// ---------------------------------------------------------------------------
// Kernel A: one block per batch, 4 waves, register-resident selection.
// Tournament-tree local argmax (depth 6, exact min-index ties) + butterfly
// cross-lane merge per pass; wave 0 merges 52 candidates and writes the
// batch's 13 (anchor, v) pairs to ws. Also writes the mask_pos row.
// ---------------------------------------------------------------------------
__global__ __launch_bounds__(256) void assign_kernel(
    const float* __restrict__ pd_scores,   // (BS, NC, NA)
    const float* __restrict__ pd_bboxes,   // (BS, 4, NA)
    const int*   __restrict__ gt_labels,   // (BS,)
    const float* __restrict__ gt_bboxes,   // (BS, 4)
    float*       __restrict__ out_mask,    // (BS, NA) = d_out + NA*BS
    float*       __restrict__ ws_v,        // (BS*TOPK,) winner v values
    int*         __restrict__ ws_i)        // (BS*TOPK,) winner anchor indices
{
    __shared__ float s_cv[4 * TOPK];
    __shared__ int   s_ci[4 * TOPK];
    __shared__ float s_cov[4 * TOPK];
    __shared__ int   s_win[TOPK];
    __shared__ float s_mask;

    const int b = blockIdx.x;
    const int t = threadIdx.x;
    const int wave = t >> 6, lane = t & 63;
    const int seg_lo = wave * SEG;
    const int seg_hi = seg_lo + SEG;

    const float p1x = gt_bboxes[b * 4 + 0];
    const float p1y = gt_bboxes[b * 4 + 1];
    const float p2x = gt_bboxes[b * 4 + 2];
    const float p2y = gt_bboxes[b * 4 + 3];
    const float area1 = fmaxf(p2x - p1x, 0.f) * fmaxf(p2y - p1y, 0.f);
    const int lbl = gt_labels[b];
    const float* sc = pd_scores + (size_t)b * NC * NA + (size_t)lbl * NA;
    const float* bb = pd_bboxes + (size_t)b * 4 * NA;

    // ---- phase 0: align + overlap straight into registers (coalesced) ----
    float lv[KMAX], lov[KMAX];
    #pragma unroll
    for (int k = 0; k < KMAX; ++k) {
        int a = seg_lo + lane + (k << 6);
        bool ok = a < seg_hi;
        int aa = ok ? a : seg_lo;
        float g1x = bb[0 * NA + aa];
        float g1y = bb[1 * NA + aa];
        float g2x = bb[2 * NA + aa];
        float g2y = bb[3 * NA + aa];
        float wx = fmaxf(fminf(p2x, g2x) - fmaxf(p1x, g1x), 0.f);
        float wy = fmaxf(fminf(p2y, g2y) - fmaxf(p1y, g1y), 0.f);
        float ovl = wx * wy;
        float area2 = fmaxf(g2x - g1x, 0.f) * fmaxf(g2y - g1y, 0.f);
        float o = ovl / (area1 + area2 - ovl + EPSF);
        float o2 = o * o;
        float score = sc[aa];
        lv[k]  = ok ? score * (o2 * o2 * o2) : -1.0f;   // valid align >= 0
        lov[k] = o;
    }

    // ---- phase 1: 13 wave-local argmax passes, zero barriers ----
    unsigned long long selmask = 0ULL;
    float cand_v = -2.f; int cand_i = 0x7fffffff; float cand_ov = 0.f;
    for (int j = 0; j < TOPK; ++j) {
        // depth-6 tournament tree over 33 leaves; (v,k,ov), ties -> min k.
        float tv[17]; int tk[17]; float tvo[17];
        #pragma unroll
        for (int i = 0; i < 16; ++i) {
            int k0 = 2 * i, k1 = 2 * i + 1;
            float v0 = ((selmask >> k0) & 1ULL) ? -2.f : lv[k0];
            float v1 = ((selmask >> k1) & 1ULL) ? -2.f : lv[k1];
            bool take0 = v0 >= v1;                    // k0 < k1: tie -> k0
            tv[i]  = take0 ? v0 : v1;
            tk[i]  = take0 ? k0 : k1;
            tvo[i] = take0 ? lov[k0] : lov[k1];
        }
        tv[16]  = ((selmask >> 32) & 1ULL) ? -2.f : lv[32];
        tk[16]  = 32;
        tvo[16] = lov[32];
        #pragma unroll
        for (int n = 17; n > 1; n = (n + 1) / 2) {
            #pragma unroll
            for (int i = 0; i < n / 2; ++i) {
                int i0 = 2 * i, i1 = 2 * i + 1;
                bool take0 = (tv[i0] > tv[i1]) ||
                             (tv[i0] == tv[i1] && tk[i0] < tk[i1]);
                tv[i]  = take0 ? tv[i0]  : tv[i1];
                tk[i]  = take0 ? tk[i0]  : tk[i1];
                tvo[i] = take0 ? tvo[i0] : tvo[i1];
            }
            if (n & 1) { tv[n / 2] = tv[n - 1]; tk[n / 2] = tk[n - 1]; tvo[n / 2] = tvo[n - 1]; }
        }
        int   mk = tk[0];
        int   mi = seg_lo + lane + (mk << 6);         // global anchor index
        float bv = tv[0]; int bi = mi; float bov = tvo[0];
        #pragma unroll
        for (int off = 1; off < 64; off <<= 1) {
            float ov_ = __shfl_xor(bv, off);
            int   oi_ = __shfl_xor(bi, off);
            float oo_ = __shfl_xor(bov, off);
            if (ov_ > bv || (ov_ == bv && oi_ < bi)) { bv = ov_; bi = oi_; bov = oo_; }
        }
        if (mi == bi) selmask |= 1ULL << mk;          // owner excludes it
        if (lane == j) { cand_v = bv; cand_i = bi; cand_ov = bov; }
    }
    if (lane < TOPK) {
        s_cv [wave * TOPK + lane] = cand_v;
        s_ci [wave * TOPK + lane] = cand_i;
        s_cov[wave * TOPK + lane] = cand_ov;
    }
    __syncthreads();

    // ---- phase 2: wave 0 merges 52 candidates, writes winners to ws ----
    if (wave == 0) {
        const int NC4 = 4 * TOPK;
        float v  = lane < NC4 ? s_cv[lane]  : -2.f;
        int   ci = lane < NC4 ? s_ci[lane]  : 0x7fffffff;
        float ov = lane < NC4 ? s_cov[lane] : 0.f;
        float pos_align = 0.f, pos_ov = 0.f;
        float wv_sel = 0.f; int wi_sel = 0;
        for (int j = 0; j < TOPK; ++j) {
            float bv = v; int bi = ci; float bov = ov;
            #pragma unroll
            for (int off = 1; off < 64; off <<= 1) {
                float ov_ = __shfl_xor(bv, off);
                int   oi_ = __shfl_xor(bi, off);
                float oo_ = __shfl_xor(bov, off);
                if (ov_ > bv || (ov_ == bv && oi_ < bi)) { bv = ov_; bi = oi_; bov = oo_; }
            }
            if (j == 0) pos_align = bv;               // top-1 = row max
            pos_ov = fmaxf(pos_ov, bov);
            if (lane == j) { wv_sel = bv; wi_sel = bi; }
            if (ci == bi) v = -2.f;                   // exclude winner
        }
        float mask = pos_align > EPSF ? 1.f : 0.f;
        if (lane == 0) s_mask = mask;
        if (lane < TOPK) {
            s_win[lane] = wi_sel;
            float vv = (mask != 0.f) ? (wv_sel * pos_ov) / (pos_align + EPSF) : 0.f;
            ws_v[b * TOPK + lane] = vv;               // vv >= 0
            ws_i[b * TOPK + lane] = wi_sel;
        }
    }
    __syncthreads();

    // ---- phase 3: mask row write ----
    const float maskf = s_mask;
    int w0  = s_win[0],  w1  = s_win[1],  w2  = s_win[2],  w3 = s_win[3];
    int w4  = s_win[4],  w5  = s_win[5],  w6  = s_win[6],  w7 = s_win[7];
    int w8  = s_win[8],  w9  = s_win[9],  w10 = s_win[10], w11 = s_win[11];
    int w12 = s_win[12];
    float* om = out_mask + (size_t)b * NA;
    #pragma unroll
    for (int k = 0; k < KMAX; ++k) {
        int a = seg_lo + lane + (k << 6);
        if (a < seg_hi) {
            bool sel = (a == w0) | (a == w1) | (a == w2) | (a == w3) |
                       (a == w4) | (a == w5) | (a == w6) | (a == w7) |
                       (a == w8) | (a == w9) | (a == w10) | (a == w11) |
                       (a == w12);
            om[a] = (sel && maskf > 0.5f) ? 1.0f : 0.0f;
        }
    }
}

// ---------------------------------------------------------------------------
// Kernel B: 105 blocks x 80 anchors. Builds norm slice in LDS from the 832
// winner pairs (LDS atomicMax on float bits, all values >= 0), then writes
// out0[a*64+b] = float(gt_labels[b]) * norm[a], coalesced.
// ---------------------------------------------------------------------------
#define ABLK 80
__global__ __launch_bounds__(256) void scores_kernel(
    const float* __restrict__ ws_v,
    const int*   __restrict__ ws_i,
    const int*   __restrict__ gt_labels,
    float*       __restrict__ out0)       // (NA, BS)
{
    __shared__ int   s_norm[ABLK];        // float bits, init 0 (= 0.0f)
    __shared__ float s_lbl[BS];

    const int t  = threadIdx.x;
    const int a0 = blockIdx.x * ABLK;

    if (t < ABLK) s_norm[t] = 0;
    if (t < BS)   s_lbl[t]  = (float)gt_labels[t];
    __syncthreads();

    #pragma unroll
    for (int e = t; e < BS * TOPK; e += 256) {
        int idx = ws_i[e];
        unsigned r = (unsigned)(idx - a0);
        if (r < ABLK) atomicMax(&s_norm[r], __float_as_int(ws_v[e]));
    }
    __syncthreads();

    float* o = out0 + (size_t)a0 * BS;
    #pragma unroll
    for (int i = t; i < ABLK * BS; i += 256) {
        o[i] = s_lbl[i & (BS - 1)] * __int_as_float(s_norm[i >> 6]);
    }
}

extern "C" void kernel_launch(void* const* d_in, const int* in_sizes, int n_in,
                              void* d_out, int out_size, void* d_ws, size_t ws_size,
                              hipStream_t stream) {
    const float* pd_scores = (const float*)d_in[0];
    const float* pd_bboxes = (const float*)d_in[1];
    const int*   gt_labels = (const int*)d_in[2];
    const float* gt_bboxes = (const float*)d_in[3];

    float* out0     = (float*)d_out;                  // (NA, BS)
    float* out_mask = out0 + (size_t)NA * BS;         // (BS, NA)
    float* ws_v     = (float*)d_ws;                   // (BS*TOPK,)
    int*   ws_i     = (int*)((char*)d_ws + BS * TOPK * sizeof(float));

    assign_kernel<<<BS, 256, 0, stream>>>(pd_scores, pd_bboxes, gt_labels,
                                          gt_bboxes, out_mask, ws_v, ws_i);
    scores_kernel<<<NA / ABLK, 256, 0, stream>>>(ws_v, ws_i, gt_labels, out0);
}

// Round 5
// 235.245 us; speedup vs baseline: 1.3108x; 1.3108x over previous
//
#include <hip/hip_runtime.h>
#include <hip/hip_bf16.h>

#define NA 8400
#define BS 64
#define NC 80
#define TOPK 13
#define EPSF 1e-9f
#define NWAVE 16
#define SEG 525           // NA / NWAVE
#define KMAX 9            // ceil(SEG/64); k=8 covers lanes 0..12

// ---------------------------------------------------------------------------
// Kernel A: one block per batch, 16 waves (4/SIMD -> latency hiding).
// Wave w owns anchors [w*525, (w+1)*525): lane holds <=9 align values in
// registers (no spill), 13 barrier-free wave argmax passes -> per-wave top-13;
// wave 0 merges 208 candidates, recomputes winner overlaps from global,
// writes the batch's 13 (anchor, v) pairs to ws + the mask_pos row.
// ---------------------------------------------------------------------------
__global__ __launch_bounds__(1024) void assign_kernel(
    const float* __restrict__ pd_scores,   // (BS, NC, NA)
    const float* __restrict__ pd_bboxes,   // (BS, 4, NA)
    const int*   __restrict__ gt_labels,   // (BS,)
    const float* __restrict__ gt_bboxes,   // (BS, 4)
    float*       __restrict__ out_mask,    // (BS, NA) = d_out + NA*BS
    float*       __restrict__ ws_v,        // (BS*TOPK,) winner v values
    int*         __restrict__ ws_i)        // (BS*TOPK,) winner anchor indices
{
    __shared__ float s_cv[NWAVE * TOPK];
    __shared__ int   s_ci[NWAVE * TOPK];
    __shared__ int   s_win[TOPK];
    __shared__ float s_mask;

    const int b = blockIdx.x;
    const int t = threadIdx.x;
    const int wave = t >> 6, lane = t & 63;
    const int seg_lo = wave * SEG;
    const int seg_hi = seg_lo + SEG;

    const float p1x = gt_bboxes[b * 4 + 0];
    const float p1y = gt_bboxes[b * 4 + 1];
    const float p2x = gt_bboxes[b * 4 + 2];
    const float p2y = gt_bboxes[b * 4 + 3];
    const float area1 = fmaxf(p2x - p1x, 0.f) * fmaxf(p2y - p1y, 0.f);
    const int lbl = gt_labels[b];
    const float* sc = pd_scores + (size_t)b * NC * NA + (size_t)lbl * NA;
    const float* bb = pd_bboxes + (size_t)b * 4 * NA;

    // ---- phase 0: align metric into registers (coalesced, 9/lane) ----
    float lv[KMAX];
    #pragma unroll
    for (int k = 0; k < KMAX; ++k) {
        int a = seg_lo + lane + (k << 6);
        bool ok = a < seg_hi;
        int aa = ok ? a : seg_lo;
        float g1x = bb[0 * NA + aa];
        float g1y = bb[1 * NA + aa];
        float g2x = bb[2 * NA + aa];
        float g2y = bb[3 * NA + aa];
        float wx = fmaxf(fminf(p2x, g2x) - fmaxf(p1x, g1x), 0.f);
        float wy = fmaxf(fminf(p2y, g2y) - fmaxf(p1y, g1y), 0.f);
        float ovl = wx * wy;
        float area2 = fmaxf(g2x - g1x, 0.f) * fmaxf(g2y - g1y, 0.f);
        float o = ovl / (area1 + area2 - ovl + EPSF);
        float o2 = o * o;
        lv[k] = ok ? sc[aa] * (o2 * o2 * o2) : -1.0f;   // valid align >= 0
    }

    // ---- phase 1: 13 wave-local argmax passes, zero barriers ----
    unsigned selmask = 0;
    float cand_v = -2.f; int cand_i = 0x7fffffff;
    for (int j = 0; j < TOPK; ++j) {
        float mv = -2.f; int mk = 0;
        #pragma unroll
        for (int k = 0; k < KMAX; ++k) {
            float v = ((selmask >> k) & 1u) ? -2.f : lv[k];
            if (v > mv) { mv = v; mk = k; }   // strict > : smallest k (= smallest a)
        }
        int mi = seg_lo + lane + (mk << 6);
        float bv = mv; int bi = mi;
        #pragma unroll
        for (int off = 1; off < 64; off <<= 1) {
            float ov_ = __shfl_xor(bv, off);
            int   oi_ = __shfl_xor(bi, off);
            if (ov_ > bv || (ov_ == bv && oi_ < bi)) { bv = ov_; bi = oi_; }
        }
        if (mi == bi) selmask |= 1u << mk;    // owner excludes its element
        if (lane == j) { cand_v = bv; cand_i = bi; }
    }
    if (lane < TOPK) {
        s_cv[wave * TOPK + lane] = cand_v;
        s_ci[wave * TOPK + lane] = cand_i;
    }
    __syncthreads();

    // ---- phase 2: wave 0 merges 208 candidates (4 slots/lane) ----
    if (wave == 0) {
        const int NCAND = NWAVE * TOPK;       // 208
        float cv[4]; int ci[4];
        #pragma unroll
        for (int s = 0; s < 4; ++s) {
            int e = lane + (s << 6);
            bool ok = e < NCAND;
            cv[s] = ok ? s_cv[e] : -2.f;
            ci[s] = ok ? s_ci[e] : 0x7fffffff;
        }
        float pos_align = 0.f;
        float wv_sel = 0.f; int wi_sel = 0;
        for (int j = 0; j < TOPK; ++j) {
            float mv = -2.f; int mi = 0x7fffffff;
            #pragma unroll
            for (int s = 0; s < 4; ++s) {
                if (cv[s] > mv || (cv[s] == mv && ci[s] < mi)) { mv = cv[s]; mi = ci[s]; }
            }
            float bv = mv; int bi = mi;
            #pragma unroll
            for (int off = 1; off < 64; off <<= 1) {
                float ov_ = __shfl_xor(bv, off);
                int   oi_ = __shfl_xor(bi, off);
                if (ov_ > bv || (ov_ == bv && oi_ < bi)) { bv = ov_; bi = oi_; }
            }
            if (j == 0) pos_align = bv;       // top-1 = row max
            if (lane == j) { wv_sel = bv; wi_sel = bi; }
            #pragma unroll
            for (int s = 0; s < 4; ++s) if (ci[s] == bi) cv[s] = -2.f; // exclude
        }
        // recompute overlaps for the 13 winners (same f32 op sequence)
        float myov = 0.f;
        if (lane < TOPK) {
            int a = wi_sel;
            float g1x = bb[0 * NA + a];
            float g1y = bb[1 * NA + a];
            float g2x = bb[2 * NA + a];
            float g2y = bb[3 * NA + a];
            float wx = fmaxf(fminf(p2x, g2x) - fmaxf(p1x, g1x), 0.f);
            float wy = fmaxf(fminf(p2y, g2y) - fmaxf(p1y, g1y), 0.f);
            float ovl = wx * wy;
            float area2 = fmaxf(g2x - g1x, 0.f) * fmaxf(g2y - g1y, 0.f);
            myov = ovl / (area1 + area2 - ovl + EPSF);   // >= 0
        }
        float pov = myov;                      // lanes 13..15 contribute 0
        #pragma unroll
        for (int off = 1; off < 16; off <<= 1) pov = fmaxf(pov, __shfl_xor(pov, off));
        float mask = pos_align > EPSF ? 1.f : 0.f;
        if (lane == 0) s_mask = mask;
        if (lane < TOPK) {
            s_win[lane] = wi_sel;
            float vv = (mask != 0.f) ? (wv_sel * pov) / (pos_align + EPSF) : 0.f;
            ws_v[b * TOPK + lane] = vv;        // vv >= 0
            ws_i[b * TOPK + lane] = wi_sel;
        }
    }
    __syncthreads();

    // ---- phase 3: mask row write (1024 threads, coalesced) ----
    const float maskf = s_mask;
    int w0  = s_win[0],  w1  = s_win[1],  w2  = s_win[2],  w3 = s_win[3];
    int w4  = s_win[4],  w5  = s_win[5],  w6  = s_win[6],  w7 = s_win[7];
    int w8  = s_win[8],  w9  = s_win[9],  w10 = s_win[10], w11 = s_win[11];
    int w12 = s_win[12];
    float* om = out_mask + (size_t)b * NA;
    for (int a = t; a < NA; a += 1024) {
        bool sel = (a == w0) | (a == w1) | (a == w2) | (a == w3) |
                   (a == w4) | (a == w5) | (a == w6) | (a == w7) |
                   (a == w8) | (a == w9) | (a == w10) | (a == w11) |
                   (a == w12);
        om[a] = (sel && maskf > 0.5f) ? 1.0f : 0.0f;
    }
}

// ---------------------------------------------------------------------------
// Kernel B: 105 blocks x 80 anchors. Builds norm slice in LDS from the 832
// winner pairs (LDS atomicMax on float bits, all values >= 0), then writes
// out0[a*64+b] = float(gt_labels[b]) * norm[a], coalesced.
// ---------------------------------------------------------------------------
#define ABLK 80
__global__ __launch_bounds__(256) void scores_kernel(
    const float* __restrict__ ws_v,
    const int*   __restrict__ ws_i,
    const int*   __restrict__ gt_labels,
    float*       __restrict__ out0)       // (NA, BS)
{
    __shared__ int   s_norm[ABLK];        // float bits, init 0 (= 0.0f)
    __shared__ float s_lbl[BS];

    const int t  = threadIdx.x;
    const int a0 = blockIdx.x * ABLK;

    if (t < ABLK) s_norm[t] = 0;
    if (t < BS)   s_lbl[t]  = (float)gt_labels[t];
    __syncthreads();

    #pragma unroll
    for (int e = t; e < BS * TOPK; e += 256) {
        int idx = ws_i[e];
        unsigned r = (unsigned)(idx - a0);
        if (r < ABLK) atomicMax(&s_norm[r], __float_as_int(ws_v[e]));
    }
    __syncthreads();

    float* o = out0 + (size_t)a0 * BS;
    #pragma unroll
    for (int i = t; i < ABLK * BS; i += 256) {
        o[i] = s_lbl[i & (BS - 1)] * __int_as_float(s_norm[i >> 6]);
    }
}

extern "C" void kernel_launch(void* const* d_in, const int* in_sizes, int n_in,
                              void* d_out, int out_size, void* d_ws, size_t ws_size,
                              hipStream_t stream) {
    const float* pd_scores = (const float*)d_in[0];
    const float* pd_bboxes = (const float*)d_in[1];
    const int*   gt_labels = (const int*)d_in[2];
    const float* gt_bboxes = (const float*)d_in[3];

    float* out0     = (float*)d_out;                  // (NA, BS)
    float* out_mask = out0 + (size_t)NA * BS;         // (BS, NA)
    float* ws_v     = (float*)d_ws;                   // (BS*TOPK,)
    int*   ws_i     = (int*)((char*)d_ws + BS * TOPK * sizeof(float));

    assign_kernel<<<BS, 1024, 0, stream>>>(pd_scores, pd_bboxes, gt_labels,
                                           gt_bboxes, out_mask, ws_v, ws_i);
    scores_kernel<<<NA / ABLK, 256, 0, stream>>>(ws_v, ws_i, gt_labels, out0);
}